// Round 4
// baseline (450.579 us; speedup 1.0000x reference)
//
#include <hip/hip_runtime.h>
#include <math.h>

#define T_DIM 16384
#define A_DIM 128
#define K_DIM 128
#define N_STEPS 16
#define E_DIM 126
#define NSEQ 4

// tiles: 16 atoms x 256 t  -> 8 atiles x 64 ttiles = 512 tiles/seq
#define ATI 16
#define TT 256
#define NTT 64
#define NPT 512                 // tiles per seq
#define INC_B 16                // inc blocks per seq (8 atiles x 2 parity)

// order-preserving pack: bigger u64 == (bigger value, then smaller flat idx)
__device__ inline unsigned long long pack_vi(float v, int fi) {
    unsigned int b = __float_as_uint(v);
    b = (b & 0x80000000u) ? ~b : (b | 0x80000000u);
    return ((unsigned long long)b << 32) | (unsigned int)(~fi);
}
__device__ inline void unpack_vi(unsigned long long p, float* v, int* fi) {
    unsigned int lo = (unsigned int)(p & 0xffffffffu);
    unsigned int b = (unsigned int)(p >> 32);
    unsigned int fb = (b & 0x80000000u) ? (b & 0x7fffffffu) : ~b;
    *v = __uint_as_float(fb);
    *fi = (int)(~lo);
}

// ---------------------------------------------------------------------------
// fused: d_unit rows (blocks 0..127), res init + ctrl zero (blocks 128..383)
__global__ __launch_bounds__(256) void k_prep(
    const float* __restrict__ d, const float* __restrict__ a,
    const float* __restrict__ b, float* __restrict__ du,
    float* __restrict__ res, int* __restrict__ ctrl, int* __restrict__ dirty) {
    int blk = blockIdx.x, tid = threadIdx.x;
    if (blk < 128) {
        __shared__ float s[128];
        float v = 0.0f;
        if (tid < 128) { v = d[blk * K_DIM + tid]; s[tid] = v * v; }
        __syncthreads();
        for (int off = 64; off > 0; off >>= 1) {
            if (tid < off) s[tid] += s[tid + off];
            __syncthreads();
        }
        if (tid < 128) du[blk * K_DIM + tid] = v / (sqrtf(s[0]) + 1e-8f);
    } else {
        int i = (blk - 128) * 256 + tid;      // 0..65535
        res[i] = (i < 2 * T_DIM) ? a[i] : b[i - 2 * T_DIM];
        if (blk == 128) {
            if (tid < 4 + N_STEPS * NSEQ + 4) ctrl[tid] = 0;  // cnt[4] arrive[64] release[4]
            if (tid < 2 * NSEQ) dirty[tid] = (tid & 1) ? T_DIM : 0;
        }
    }
}

// ---------------------------------------------------------------------------
// compute one 16a x 256t tile; du_sh pre-staged. k ascending per acc -> fm
// values bit-identical to the k+=2 version. Returns packed block argmax.
__device__ inline unsigned long long tile16(
    const float* __restrict__ res, const float* __restrict__ du_sh,
    int seq, int a_base, int t0, int tid,
    float* res_sh, float* rv_sh, int* ri_sh) {

    const float* resS = res + seq * T_DIM;
    for (int i = tid; i < TT + K_DIM - 1; i += 256) {
        int t = t0 + i - K_DIM / 2;
        res_sh[i] = (t >= 0 && t < T_DIM) ? resS[t] : 0.0f;
    }
    __syncthreads();

    int tg = tid & 63;
    int a0 = (tid >> 6) * 4;      // wave-uniform -> du broadcast reads

    float acc[4][4];
    #pragma unroll
    for (int i = 0; i < 4; i++)
        #pragma unroll
        for (int j = 0; j < 4; j++) acc[i][j] = 0.0f;

    for (int k = 0; k < K_DIM; k += 4) {
        float4 dv[4];
        #pragma unroll
        for (int i = 0; i < 4; i++)
            dv[i] = *(const float4*)&du_sh[(a0 + i) * K_DIM + k];
        #pragma unroll
        for (int j = 0; j < 4; j++) {
            float r0 = res_sh[tg + 64 * j + k + 0];
            float r1 = res_sh[tg + 64 * j + k + 1];
            float r2 = res_sh[tg + 64 * j + k + 2];
            float r3 = res_sh[tg + 64 * j + k + 3];
            #pragma unroll
            for (int i = 0; i < 4; i++) {
                acc[i][j] = fmaf(dv[i].x, r0, acc[i][j]);
                acc[i][j] = fmaf(dv[i].y, r1, acc[i][j]);
                acc[i][j] = fmaf(dv[i].z, r2, acc[i][j]);
                acc[i][j] = fmaf(dv[i].w, r3, acc[i][j]);
            }
        }
    }

    float bv = -INFINITY;
    int bi = 0x7fffffff;
    #pragma unroll
    for (int i = 0; i < 4; i++) {          // ascending fi order
        int a = a_base + a0 + i;
        #pragma unroll
        for (int j = 0; j < 4; j++) {
            int t = t0 + tg + 64 * j;
            int fi = a * T_DIM + t;
            float v = acc[i][j];
            if (v > bv || (v == bv && fi < bi)) { bv = v; bi = fi; }
        }
    }
    rv_sh[tid] = bv;
    ri_sh[tid] = bi;
    __syncthreads();
    for (int off = 128; off > 0; off >>= 1) {
        if (tid < off) {
            float v2 = rv_sh[tid + off]; int i2 = ri_sh[tid + off];
            if (v2 > rv_sh[tid] || (v2 == rv_sh[tid] && i2 < ri_sh[tid])) {
                rv_sh[tid] = v2; ri_sh[tid] = i2;
            }
        }
        __syncthreads();
    }
    return pack_vi(rv_sh[0], ri_sh[0]);
}

__device__ inline void finalize_step(
    unsigned long long p, int step, int seq, int tid,
    const float* __restrict__ du, const float* __restrict__ ae,
    float* __restrict__ emb, float* __restrict__ res, int* __restrict__ dirty) {
    float value; int fi;
    unpack_vi(p, &value, &fi);
    int ai = fi >> 14;
    int ti = fi & (T_DIM - 1);
    int pos_idx = value > 0.0f ? ti : 0;
    int atom_idx = value > 0.0f ? ai : 0;

    float* e = emb + (seq * N_STEPS + step) * 128;
    if (tid == 0) {
        e[0] = ((float)pos_idx / (float)(T_DIM - 1)) * 20.0f;
        e[1] = value;
    }
    if (tid == 1 && step + 1 < N_STEPS) {
        int nlo = ti - (K_DIM - 1); if (nlo < 0) nlo = 0;
        int nhi = ti + K_DIM;       if (nhi > T_DIM) nhi = T_DIM;
        dirty[(step + 1) * 2 * NSEQ + seq * 2 + 0] = nlo;
        dirty[(step + 1) * 2 * NSEQ + seq * 2 + 1] = nhi;
    }
    if (tid >= 2 && tid < 2 + E_DIM) e[tid] = ae[atom_idx * E_DIM + tid - 2];
    if (tid >= 128) {
        int k = tid - 128;
        int t = ti + k - K_DIM / 2;
        if (t >= 0 && t < T_DIM) res[seq * T_DIM + t] -= value * du[ai * K_DIM + k];
    }
}

// ---------------------------------------------------------------------------
// step 0: 512 blocks/seq; last-arriving block per seq reduces pmax + finalizes
__global__ __launch_bounds__(256) void k_step_full(
    float* __restrict__ res, const float* __restrict__ du,
    const float* __restrict__ ae, float* __restrict__ emb,
    unsigned long long* __restrict__ pmax, int* __restrict__ cnt,
    int* __restrict__ dirty) {

    int seq = blockIdx.y;
    int blk = blockIdx.x;                 // 0..511
    int a_base = (blk >> 6) * ATI;
    int t0 = (blk & 63) * TT;
    int tid = threadIdx.x;

    __shared__ float du_sh[ATI * K_DIM];   // 8 KB
    __shared__ float res_sh[TT + K_DIM];
    __shared__ float rv_sh[256];
    __shared__ int   ri_sh[256];
    __shared__ unsigned long long pm_sh[256];
    __shared__ int last_flag;

    for (int i = tid; i < ATI * K_DIM; i += 256) du_sh[i] = du[a_base * K_DIM + i];
    // tile16's internal __syncthreads (after res staging) covers du_sh too
    unsigned long long p = tile16(res, du_sh, seq, a_base, t0, tid,
                                  res_sh, rv_sh, ri_sh);
    if (tid == 0) {
        pmax[seq * NPT + blk] = p;
        __threadfence();
        last_flag = (atomicAdd(&cnt[seq], 1) == NPT - 1);
    }
    __syncthreads();
    if (!last_flag) return;

    __threadfence();
    {
        unsigned long long m0 = pmax[seq * NPT + tid];
        unsigned long long m1 = pmax[seq * NPT + 256 + tid];
        pm_sh[tid] = m0 > m1 ? m0 : m1;
    }
    __syncthreads();
    for (int off = 128; off > 0; off >>= 1) {
        if (tid < off) { if (pm_sh[tid + off] > pm_sh[tid]) pm_sh[tid] = pm_sh[tid + off]; }
        __syncthreads();
    }
    finalize_step(pm_sh[0], 0, seq, tid, du, ae, emb, res, dirty);
}

// ---------------------------------------------------------------------------
// persistent steps 1..15: 16 blocks/seq, du staged once, per-seq barriers via
// arrive counters + release flag (write -> fence -> atomic-signal pattern).
__global__ __launch_bounds__(256) void k_inc(
    float* __restrict__ res, const float* __restrict__ du,
    const float* __restrict__ ae, float* __restrict__ emb,
    unsigned long long* __restrict__ pmax, int* __restrict__ arrive,
    int* __restrict__ release, int* __restrict__ dirty) {

    int seq = blockIdx.y;
    int blk = blockIdx.x;                 // 0..15
    int atile = blk >> 1;                 // 0..7
    int par = blk & 1;
    int a_base = atile * ATI;
    int tid = threadIdx.x;

    __shared__ float du_sh[ATI * K_DIM];
    __shared__ float res_sh[TT + K_DIM];
    __shared__ float rv_sh[256];
    __shared__ int   ri_sh[256];
    __shared__ unsigned long long pm_sh[256];
    __shared__ int go_sh;

    for (int i = tid; i < ATI * K_DIM; i += 256) du_sh[i] = du[a_base * K_DIM + i];

    for (int step = 1; step < N_STEPS; step++) {
        __syncthreads();   // du_sh staged / previous-iter LDS reuse complete

        int lo = dirty[step * 2 * NSEQ + seq * 2 + 0];
        int hi = dirty[step * 2 * NSEQ + seq * 2 + 1];
        int ttile = (lo >> 8) + par;                 // window <=255 -> <=2 ttiles
        bool valid = (ttile < NTT) && (ttile * TT < hi);

        if (valid) {
            unsigned long long p = tile16(res, du_sh, seq, a_base, ttile * TT,
                                          tid, res_sh, rv_sh, ri_sh);
            if (tid == 0) pmax[seq * NPT + atile * NTT + ttile] = p;
        }
        if (tid == 0) {
            __threadfence();
            go_sh = (atomicAdd(&arrive[step * NSEQ + seq], 1) == INC_B - 1);
        }
        __syncthreads();

        if (go_sh) {
            __threadfence();
            unsigned long long m0 = pmax[seq * NPT + tid];
            unsigned long long m1 = pmax[seq * NPT + 256 + tid];
            pm_sh[tid] = m0 > m1 ? m0 : m1;
            __syncthreads();
            for (int off = 128; off > 0; off >>= 1) {
                if (tid < off) { if (pm_sh[tid + off] > pm_sh[tid]) pm_sh[tid] = pm_sh[tid + off]; }
                __syncthreads();
            }
            finalize_step(pm_sh[0], step, seq, tid, du, ae, emb, res, dirty);
            __threadfence();               // res/emb/dirty writes device-visible
            __syncthreads();
            if (tid == 0) atomicAdd(&release[seq], 1);   // release step
        } else {
            if (tid == 0) {
                while (__hip_atomic_load(&release[seq], __ATOMIC_ACQUIRE,
                                         __HIP_MEMORY_SCOPE_AGENT) < step) {
                    __builtin_amdgcn_s_sleep(2);
                }
            }
            __syncthreads();
            __threadfence();               // invalidate stale cached res/dirty
        }
    }
}

// ---------------------------------------------------------------------------
// norms + ordering + loss; 1 block x 1024 threads
__global__ __launch_bounds__(1024) void k_tail(
    const float* __restrict__ res, const float* __restrict__ emb,
    const float* __restrict__ proj, float* __restrict__ out) {
    int tid = threadIdx.x;
    __shared__ float sh[1024];
    __shared__ float norms[NSEQ];
    __shared__ float keys[NSEQ][N_STEPS];
    __shared__ int   order[NSEQ][N_STEPS];

    {
        int seq = tid >> 8;
        int ln  = tid & 255;
        const float4* r4 = (const float4*)(res + seq * T_DIM);
        float s = 0.0f;
        #pragma unroll
        for (int j = 0; j < 16; j++) {
            float4 v = r4[j * 256 + ln];
            s = fmaf(v.x, v.x, s); s = fmaf(v.y, v.y, s);
            s = fmaf(v.z, v.z, s); s = fmaf(v.w, v.w, s);
        }
        sh[tid] = s;
        __syncthreads();
        for (int off = 128; off > 0; off >>= 1) {
            if (ln < off) sh[tid] += sh[tid + off];
            __syncthreads();
        }
        if (ln == 0) norms[seq] = sqrtf(sh[tid]);
        __syncthreads();
    }
    {
        int pair = tid >> 4;
        int seq = pair >> 4, st = pair & 15;
        int ln = tid & 15;
        const float* e = emb + (seq * N_STEPS + st) * 128 + ln * 8;
        const float* pr = proj + ln * 8;
        float kk = 0.0f;
        #pragma unroll
        for (int dd = 0; dd < 8; dd++) kk = fmaf(e[dd], pr[dd], kk);
        sh[tid] = kk;
        __syncthreads();
        for (int off = 8; off > 0; off >>= 1) {
            if (ln < off) sh[tid] += sh[tid + off];
            __syncthreads();
        }
        if (ln == 0) keys[seq][st] = sh[tid];
        __syncthreads();
    }
    if (tid < NSEQ) {
        int ord[N_STEPS];
        for (int i = 0; i < N_STEPS; i++) ord[i] = i;
        for (int i = 1; i < N_STEPS; i++) {
            int oi = ord[i];
            float kv = keys[tid][oi];
            int j = i - 1;
            while (j >= 0 && keys[tid][ord[j]] > kv) { ord[j + 1] = ord[j]; j--; }
            ord[j + 1] = oi;
        }
        for (int i = 0; i < N_STEPS; i++) order[tid][i] = ord[i];
    }
    __syncthreads();
    float s = 0.0f;
    #pragma unroll
    for (int t = 0; t < 4; t++) {
        int idx = tid + t * 1024;
        int b  = idx >> 11;
        int st = (idx >> 7) & 15;
        int dd = idx & 127;
        float va = emb[((b    ) * N_STEPS + order[b    ][st]) * 128 + dd];
        float vb = emb[((2 + b) * N_STEPS + order[2 + b][st]) * 128 + dd];
        float df = va - vb;
        s = fmaf(df, df, s);
    }
    sh[tid] = s;
    __syncthreads();
    for (int off = 512; off > 0; off >>= 1) {
        if (tid < off) sh[tid] += sh[tid + off];
        __syncthreads();
    }
    if (tid == 0) {
        float mse = sh[0] / 4096.0f;
        float mad = 0.5f * (fabsf(norms[0] - norms[2]) + fabsf(norms[1] - norms[3]));
        out[0] = mse + mad;
    }
}

// ---------------------------------------------------------------------------
extern "C" void kernel_launch(void* const* d_in, const int* in_sizes, int n_in,
                              void* d_out, int out_size, void* d_ws, size_t ws_size,
                              hipStream_t stream) {
    const float* a    = (const float*)d_in[0];
    const float* b    = (const float*)d_in[1];
    const float* d    = (const float*)d_in[2];
    const float* ae   = (const float*)d_in[3];
    const float* proj = (const float*)d_in[4];
    float* out = (float*)d_out;

    float* ws  = (float*)d_ws;
    float* res = ws;                              // 65536 f
    float* du  = res + NSEQ * T_DIM;              // 16384 f
    float* emb = du + A_DIM * K_DIM;              // 8192 f
    unsigned long long* pmax = (unsigned long long*)(emb + NSEQ * N_STEPS * 128); // 2048 u64, 8B-aligned
    int* ctrl  = (int*)(pmax + NSEQ * NPT);       // cnt[4] | arrive[64] | release[4]
    int* cnt     = ctrl;
    int* arrive  = ctrl + 4;
    int* release = ctrl + 4 + N_STEPS * NSEQ;
    int* dirty   = ctrl + 4 + N_STEPS * NSEQ + 4; // 2*NSEQ*N_STEPS

    k_prep<<<384, 256, 0, stream>>>(d, a, b, du, res, ctrl, dirty);

    dim3 gfull(NPT, NSEQ);
    k_step_full<<<gfull, 256, 0, stream>>>(res, du, ae, emb, pmax, cnt, dirty);

    dim3 ginc(INC_B, NSEQ);
    k_inc<<<ginc, 256, 0, stream>>>(res, du, ae, emb, pmax, arrive, release, dirty);

    k_tail<<<1, 1024, 0, stream>>>(res, emb, proj, out);
}

// Round 5
// 280.183 us; speedup vs baseline: 1.6082x; 1.6082x over previous
//
#include <hip/hip_runtime.h>
#include <math.h>

#define T_DIM 16384
#define A_DIM 128
#define K_DIM 128
#define N_STEPS 16
#define E_DIM 126
#define NSEQ 4

// tiles: 16 atoms x 256 t -> 8 atiles x 64 ttiles = 512 tiles/seq
#define ATI 16
#define TT 256
#define NTT 64
#define NPT 512
#define INC_B 16     // inc blocks per seq: (atile 0..7) x (ttile parity 0..1)

// order-preserving pack: bigger u64 == (bigger value, then smaller flat idx).
// Never 0 for finite fm values -> 0 is the "empty mailbox" sentinel.
__device__ inline unsigned long long pack_vi(float v, int fi) {
    unsigned int b = __float_as_uint(v);
    b = (b & 0x80000000u) ? ~b : (b | 0x80000000u);
    return ((unsigned long long)b << 32) | (unsigned int)(~fi);
}
__device__ inline void unpack_vi(unsigned long long p, float* v, int* fi) {
    unsigned int lo = (unsigned int)(p & 0xffffffffu);
    unsigned int b = (unsigned int)(p >> 32);
    unsigned int fb = (b & 0x80000000u) ? (b & 0x7fffffffu) : ~b;
    *v = __uint_as_float(fb);
    *fi = (int)(~lo);
}

// ---------------------------------------------------------------------------
// blocks 0..127: d_unit rows; 128..383: res init; 384: zero cnt + mailboxes
__global__ __launch_bounds__(256) void k_prep(
    const float* __restrict__ d, const float* __restrict__ a,
    const float* __restrict__ b, float* __restrict__ du,
    float* __restrict__ res, int* __restrict__ cnt,
    unsigned long long* __restrict__ slots) {
    int blk = blockIdx.x, tid = threadIdx.x;
    if (blk < 128) {
        __shared__ float s[128];
        float v = 0.0f;
        if (tid < 128) { v = d[blk * K_DIM + tid]; s[tid] = v * v; }
        __syncthreads();
        for (int off = 64; off > 0; off >>= 1) {
            if (tid < off) s[tid] += s[tid + off];
            __syncthreads();
        }
        if (tid < 128) du[blk * K_DIM + tid] = v / (sqrtf(s[0]) + 1e-8f);
    } else if (blk < 384) {
        int i = (blk - 128) * 256 + tid;      // 0..65535
        res[i] = (i < 2 * T_DIM) ? a[i] : b[i - 2 * T_DIM];
    } else {
        if (tid < NSEQ) cnt[tid] = 0;
        for (int i = tid; i < (N_STEPS - 1) * NSEQ * INC_B; i += 256) slots[i] = 0ULL;
    }
}

// ---------------------------------------------------------------------------
// 16a x 256t tile; du_sh pre-staged; history (val/ti/ai of steps 1..nh) is
// replayed onto the staged res window with explicit mul-then-sub (np order).
__device__ inline unsigned long long tile16h(
    const float* __restrict__ res, const float* __restrict__ du_sh,
    const float* __restrict__ du_g, int seq, int a_base, int t0, int tid,
    float* res_sh, float* rv_sh, int* ri_sh,
    const float* val_h, const int* ti_h, const int* ai_h, int nh) {

    const float* resS = res + seq * T_DIM;
    for (int i = tid; i < TT + K_DIM - 1; i += 256) {
        int t = t0 + i - K_DIM / 2;
        float v = 0.0f;
        if (t >= 0 && t < T_DIM) {
            v = resS[t];
            for (int s = 0; s < nh; s++) {
                int dk = t - (ti_h[s] - K_DIM / 2);
                if (dk >= 0 && dk < K_DIM)
                    v = __fsub_rn(v, __fmul_rn(val_h[s], du_g[ai_h[s] * K_DIM + dk]));
            }
        }
        res_sh[i] = v;
    }
    __syncthreads();

    int tg = tid & 63;
    int a0 = (tid >> 6) * 4;      // wave-uniform -> du broadcast

    float acc[4][4];
    #pragma unroll
    for (int i = 0; i < 4; i++)
        #pragma unroll
        for (int j = 0; j < 4; j++) acc[i][j] = 0.0f;

    for (int k = 0; k < K_DIM; k += 4) {
        float4 dv[4];
        #pragma unroll
        for (int i = 0; i < 4; i++)
            dv[i] = *(const float4*)&du_sh[(a0 + i) * K_DIM + k];
        #pragma unroll
        for (int j = 0; j < 4; j++) {
            float r0 = res_sh[tg + 64 * j + k + 0];
            float r1 = res_sh[tg + 64 * j + k + 1];
            float r2 = res_sh[tg + 64 * j + k + 2];
            float r3 = res_sh[tg + 64 * j + k + 3];
            #pragma unroll
            for (int i = 0; i < 4; i++) {
                acc[i][j] = fmaf(dv[i].x, r0, acc[i][j]);
                acc[i][j] = fmaf(dv[i].y, r1, acc[i][j]);
                acc[i][j] = fmaf(dv[i].z, r2, acc[i][j]);
                acc[i][j] = fmaf(dv[i].w, r3, acc[i][j]);
            }
        }
    }

    float bv = -INFINITY;
    int bi = 0x7fffffff;
    #pragma unroll
    for (int i = 0; i < 4; i++) {
        int a = a_base + a0 + i;
        #pragma unroll
        for (int j = 0; j < 4; j++) {
            int t = t0 + tg + 64 * j;
            int fi = a * T_DIM + t;
            float v = acc[i][j];
            if (v > bv || (v == bv && fi < bi)) { bv = v; bi = fi; }
        }
    }
    rv_sh[tid] = bv;
    ri_sh[tid] = bi;
    __syncthreads();
    for (int off = 128; off > 0; off >>= 1) {
        if (tid < off) {
            float v2 = rv_sh[tid + off]; int i2 = ri_sh[tid + off];
            if (v2 > rv_sh[tid] || (v2 == rv_sh[tid] && i2 < ri_sh[tid])) {
                rv_sh[tid] = v2; ri_sh[tid] = i2;
            }
        }
        __syncthreads();
    }
    return pack_vi(rv_sh[0], ri_sh[0]);
}

// ---------------------------------------------------------------------------
// step 0: 512 blocks/seq; last arrival reduces pmax, finalizes step 0 into
// global res/emb and publishes the step-1 dirty window.
__global__ __launch_bounds__(256) void k_step_full(
    float* __restrict__ res, const float* __restrict__ du,
    const float* __restrict__ ae, float* __restrict__ emb,
    unsigned long long* __restrict__ pmax, int* __restrict__ cnt,
    int* __restrict__ dirty0) {

    int seq = blockIdx.y;
    int blk = blockIdx.x;                 // 0..511 = atile*64 + ttile
    int a_base = (blk >> 6) * ATI;
    int t0 = (blk & 63) * TT;
    int tid = threadIdx.x;

    __shared__ float du_sh[ATI * K_DIM];
    __shared__ float res_sh[TT + K_DIM];
    __shared__ float rv_sh[256];
    __shared__ int   ri_sh[256];
    __shared__ unsigned long long pm_sh[256];
    __shared__ int last_flag;

    for (int i = tid; i < ATI * K_DIM; i += 256) du_sh[i] = du[a_base * K_DIM + i];
    unsigned long long p = tile16h(res, du_sh, du, seq, a_base, t0, tid,
                                   res_sh, rv_sh, ri_sh, nullptr, nullptr, nullptr, 0);
    if (tid == 0) {
        pmax[seq * NPT + blk] = p;
        __threadfence();
        last_flag = (atomicAdd(&cnt[seq], 1) == NPT - 1);
    }
    __syncthreads();
    if (!last_flag) return;

    __threadfence();
    {
        unsigned long long m0 = pmax[seq * NPT + tid];
        unsigned long long m1 = pmax[seq * NPT + 256 + tid];
        pm_sh[tid] = m0 > m1 ? m0 : m1;
    }
    __syncthreads();
    for (int off = 128; off > 0; off >>= 1) {
        if (tid < off) { if (pm_sh[tid + off] > pm_sh[tid]) pm_sh[tid] = pm_sh[tid + off]; }
        __syncthreads();
    }
    float value; int fi;
    unpack_vi(pm_sh[0], &value, &fi);
    int ai = fi >> 14;
    int ti = fi & (T_DIM - 1);
    int pos_idx = value > 0.0f ? ti : 0;
    int atom_idx = value > 0.0f ? ai : 0;

    float* e = emb + (seq * N_STEPS + 0) * 128;
    if (tid == 0) {
        e[0] = ((float)pos_idx / (float)(T_DIM - 1)) * 20.0f;
        e[1] = value;
        int nlo = ti - (K_DIM - 1); if (nlo < 0) nlo = 0;
        int nhi = ti + K_DIM;       if (nhi > T_DIM) nhi = T_DIM;
        dirty0[seq * 2 + 0] = nlo;
        dirty0[seq * 2 + 1] = nhi;
    }
    if (tid >= 2 && tid < 2 + E_DIM) e[tid] = ae[atom_idx * E_DIM + tid - 2];
    if (tid >= 128) {
        int k = tid - 128;
        int t = ti + k - K_DIM / 2;
        if (t >= 0 && t < T_DIM) {
            float r = res[seq * T_DIM + t];
            res[seq * T_DIM + t] = __fsub_rn(r, __fmul_rn(value, du[ai * K_DIM + k]));
        }
    }
}

// ---------------------------------------------------------------------------
// persistent steps 1..15. Cross-block traffic = one u64 mailbox per block per
// step (atomicExch publish, atomicAdd(p,0) coherent polls). NO fences.
__global__ __launch_bounds__(256) void k_inc(
    float* __restrict__ res, const float* __restrict__ du,
    const float* __restrict__ ae, float* __restrict__ emb,
    const unsigned long long* __restrict__ pmax,
    unsigned long long* __restrict__ slots, const int* __restrict__ dirty0) {

    int seq = blockIdx.y;
    int blk = blockIdx.x;                 // 0..15
    int atile = blk >> 1;
    int par = blk & 1;
    int a_base = atile * ATI;
    int tid = threadIdx.x;

    __shared__ float du_sh[ATI * K_DIM];
    __shared__ float res_sh[TT + K_DIM];
    __shared__ float rv_sh[256];
    __shared__ int   ri_sh[256];
    __shared__ unsigned long long tmax[32];    // owned ttiles: par, par+2, ...
    __shared__ unsigned long long poll_sh[INC_B];
    __shared__ float val_h[N_STEPS - 1];
    __shared__ int   ti_h[N_STEPS - 1];
    __shared__ int   ai_h[N_STEPS - 1];
    __shared__ int   lo_sh, hi_sh;

    for (int i = tid; i < ATI * K_DIM; i += 256) du_sh[i] = du[a_base * K_DIM + i];
    if (tid < 32) tmax[tid] = pmax[seq * NPT + atile * NTT + par + 2 * tid];
    int lo = dirty0[seq * 2 + 0];
    int hi = dirty0[seq * 2 + 1];
    __syncthreads();

    for (int step = 1; step < N_STEPS; step++) {
        int T0 = lo >> 8;
        int tt = ((T0 & 1) == par) ? T0 : T0 + 1;   // my-parity candidate
        bool valid = (tt < NTT) && (tt * TT < hi);  // overlaps dirty window?

        if (valid) {
            unsigned long long p = tile16h(res, du_sh, du, seq, a_base, tt * TT,
                                           tid, res_sh, rv_sh, ri_sh,
                                           val_h, ti_h, ai_h, step - 1);
            if (tid == 0) tmax[(tt - par) >> 1] = p;
        }
        if (tid == 0) {
            unsigned long long m = tmax[0];
            for (int j = 1; j < 32; j++) if (tmax[j] > m) m = tmax[j];
            atomicExch(&slots[((step - 1) * NSEQ + seq) * INC_B + blk], m);
        }
        if (tid < INC_B) {
            unsigned long long* sp = &slots[((step - 1) * NSEQ + seq) * INC_B + tid];
            unsigned long long v = atomicAdd(sp, 0ULL);
            while (v == 0ULL) { __builtin_amdgcn_s_sleep(1); v = atomicAdd(sp, 0ULL); }
            poll_sh[tid] = v;
        }
        __syncthreads();
        if (tid == 0) {
            unsigned long long w = poll_sh[0];
            for (int j = 1; j < INC_B; j++) if (poll_sh[j] > w) w = poll_sh[j];
            float value; int fi;
            unpack_vi(w, &value, &fi);
            int ti = fi & (T_DIM - 1);
            val_h[step - 1] = value;
            ti_h[step - 1] = ti;
            ai_h[step - 1] = fi >> 14;
            int nlo = ti - (K_DIM - 1); if (nlo < 0) nlo = 0;
            int nhi = ti + K_DIM;       if (nhi > T_DIM) nhi = T_DIM;
            lo_sh = nlo; hi_sh = nhi;
        }
        __syncthreads();

        if (blk == 0) {   // emb row for this step
            float value = val_h[step - 1];
            int ti = ti_h[step - 1], ai = ai_h[step - 1];
            int pos_idx = value > 0.0f ? ti : 0;
            int atom_idx = value > 0.0f ? ai : 0;
            float* e = emb + (seq * N_STEPS + step) * 128;
            if (tid == 0) {
                e[0] = ((float)pos_idx / (float)(T_DIM - 1)) * 20.0f;
                e[1] = value;
            }
            if (tid >= 2 && tid < 128) e[tid] = ae[atom_idx * E_DIM + tid - 2];
        }
        lo = lo_sh; hi = hi_sh;
    }

    // write final res (updates 1..15, in step order) so k_tail sees it
    if (blk == 0) {
        __syncthreads();
        for (int s = 0; s < N_STEPS - 1; s++) {
            if (tid < 128) {
                int t = ti_h[s] - K_DIM / 2 + tid;
                if (t >= 0 && t < T_DIM) {
                    float r = res[seq * T_DIM + t];
                    res[seq * T_DIM + t] =
                        __fsub_rn(r, __fmul_rn(val_h[s], du[ai_h[s] * K_DIM + tid]));
                }
            }
            __syncthreads();
        }
    }
}

// ---------------------------------------------------------------------------
// norms + ordering + loss; 1 block x 1024 threads
__global__ __launch_bounds__(1024) void k_tail(
    const float* __restrict__ res, const float* __restrict__ emb,
    const float* __restrict__ proj, float* __restrict__ out) {
    int tid = threadIdx.x;
    __shared__ float sh[1024];
    __shared__ float norms[NSEQ];
    __shared__ float keys[NSEQ][N_STEPS];
    __shared__ int   order[NSEQ][N_STEPS];

    {
        int seq = tid >> 8;
        int ln  = tid & 255;
        const float4* r4 = (const float4*)(res + seq * T_DIM);
        float s = 0.0f;
        #pragma unroll
        for (int j = 0; j < 16; j++) {
            float4 v = r4[j * 256 + ln];
            s = fmaf(v.x, v.x, s); s = fmaf(v.y, v.y, s);
            s = fmaf(v.z, v.z, s); s = fmaf(v.w, v.w, s);
        }
        sh[tid] = s;
        __syncthreads();
        for (int off = 128; off > 0; off >>= 1) {
            if (ln < off) sh[tid] += sh[tid + off];
            __syncthreads();
        }
        if (ln == 0) norms[seq] = sqrtf(sh[tid]);
        __syncthreads();
    }
    {
        int pair = tid >> 4;
        int seq = pair >> 4, st = pair & 15;
        int ln = tid & 15;
        const float* e = emb + (seq * N_STEPS + st) * 128 + ln * 8;
        const float* pr = proj + ln * 8;
        float kk = 0.0f;
        #pragma unroll
        for (int dd = 0; dd < 8; dd++) kk = fmaf(e[dd], pr[dd], kk);
        sh[tid] = kk;
        __syncthreads();
        for (int off = 8; off > 0; off >>= 1) {
            if (ln < off) sh[tid] += sh[tid + off];
            __syncthreads();
        }
        if (ln == 0) keys[seq][st] = sh[tid];
        __syncthreads();
    }
    if (tid < NSEQ) {
        int ord[N_STEPS];
        for (int i = 0; i < N_STEPS; i++) ord[i] = i;
        for (int i = 1; i < N_STEPS; i++) {
            int oi = ord[i];
            float kv = keys[tid][oi];
            int j = i - 1;
            while (j >= 0 && keys[tid][ord[j]] > kv) { ord[j + 1] = ord[j]; j--; }
            ord[j + 1] = oi;
        }
        for (int i = 0; i < N_STEPS; i++) order[tid][i] = ord[i];
    }
    __syncthreads();
    float s = 0.0f;
    #pragma unroll
    for (int t = 0; t < 4; t++) {
        int idx = tid + t * 1024;
        int b  = idx >> 11;
        int st = (idx >> 7) & 15;
        int dd = idx & 127;
        float va = emb[((b    ) * N_STEPS + order[b    ][st]) * 128 + dd];
        float vb = emb[((2 + b) * N_STEPS + order[2 + b][st]) * 128 + dd];
        float df = va - vb;
        s = fmaf(df, df, s);
    }
    sh[tid] = s;
    __syncthreads();
    for (int off = 512; off > 0; off >>= 1) {
        if (tid < off) sh[tid] += sh[tid + off];
        __syncthreads();
    }
    if (tid == 0) {
        float mse = sh[0] / 4096.0f;
        float mad = 0.5f * (fabsf(norms[0] - norms[2]) + fabsf(norms[1] - norms[3]));
        out[0] = mse + mad;
    }
}

// ---------------------------------------------------------------------------
extern "C" void kernel_launch(void* const* d_in, const int* in_sizes, int n_in,
                              void* d_out, int out_size, void* d_ws, size_t ws_size,
                              hipStream_t stream) {
    const float* a    = (const float*)d_in[0];
    const float* b    = (const float*)d_in[1];
    const float* d    = (const float*)d_in[2];
    const float* ae   = (const float*)d_in[3];
    const float* proj = (const float*)d_in[4];
    float* out = (float*)d_out;

    float* ws  = (float*)d_ws;
    float* res = ws;                              // 65536 f
    float* du  = res + NSEQ * T_DIM;              // 16384 f
    float* emb = du + A_DIM * K_DIM;              // 8192 f
    unsigned long long* pmax  = (unsigned long long*)(emb + NSEQ * N_STEPS * 128); // 2048 u64
    unsigned long long* slots = pmax + NSEQ * NPT;                                 // 960 u64
    int* cnt    = (int*)(slots + (N_STEPS - 1) * NSEQ * INC_B);
    int* dirty0 = cnt + NSEQ;                     // 8 ints

    k_prep<<<385, 256, 0, stream>>>(d, a, b, du, res, cnt, slots);

    dim3 gfull(NPT, NSEQ);
    k_step_full<<<gfull, 256, 0, stream>>>(res, du, ae, emb, pmax, cnt, dirty0);

    dim3 ginc(INC_B, NSEQ);
    k_inc<<<ginc, 256, 0, stream>>>(res, du, ae, emb, pmax, slots, dirty0);

    k_tail<<<1, 1024, 0, stream>>>(res, emb, proj, out);
}

// Round 6
// 260.460 us; speedup vs baseline: 1.7299x; 1.0757x over previous
//
#include <hip/hip_runtime.h>
#include <math.h>

#define T_DIM 16384
#define A_DIM 128
#define K_DIM 128
#define N_STEPS 16
#define E_DIM 126
#define NSEQ 4

// tiles: 16 atoms x 256 t -> 8 atiles x 64 ttiles = 512 tiles/seq
#define ATI 16
#define TT 256
#define NTT 64
#define NPT 512
#define INC_B 16     // inc blocks per seq: (atile 0..7) x (ttile parity 0..1)
#define RS_PAD 392   // staged res window: 383 used, padded for trailing b128

// order-preserving pack: bigger u64 == (bigger value, then smaller flat idx).
// Never 0 for finite fm values -> 0 is the "empty mailbox" sentinel.
__device__ inline unsigned long long pack_vi(float v, int fi) {
    unsigned int b = __float_as_uint(v);
    b = (b & 0x80000000u) ? ~b : (b | 0x80000000u);
    return ((unsigned long long)b << 32) | (unsigned int)(~fi);
}
__device__ inline void unpack_vi(unsigned long long p, float* v, int* fi) {
    unsigned int lo = (unsigned int)(p & 0xffffffffu);
    unsigned int b = (unsigned int)(p >> 32);
    unsigned int fb = (b & 0x80000000u) ? (b & 0x7fffffffu) : ~b;
    *v = __uint_as_float(fb);
    *fi = (int)(~lo);
}

// ---------------------------------------------------------------------------
// blocks 0..127: d_unit rows; 128..383: res init; 384: zero cnt + mailboxes
__global__ __launch_bounds__(256) void k_prep(
    const float* __restrict__ d, const float* __restrict__ a,
    const float* __restrict__ b, float* __restrict__ du,
    float* __restrict__ res, int* __restrict__ cnt,
    unsigned long long* __restrict__ slots) {
    int blk = blockIdx.x, tid = threadIdx.x;
    if (blk < 128) {
        __shared__ float s[128];
        float v = 0.0f;
        if (tid < 128) { v = d[blk * K_DIM + tid]; s[tid] = v * v; }
        __syncthreads();
        for (int off = 64; off > 0; off >>= 1) {
            if (tid < off) s[tid] += s[tid + off];
            __syncthreads();
        }
        if (tid < 128) du[blk * K_DIM + tid] = v / (sqrtf(s[0]) + 1e-8f);
    } else if (blk < 384) {
        int i = (blk - 128) * 256 + tid;      // 0..65535
        res[i] = (i < 2 * T_DIM) ? a[i] : b[i - 2 * T_DIM];
    } else {
        if (tid < NSEQ) cnt[tid] = 0;
        for (int i = tid; i < (N_STEPS - 1) * NSEQ * INC_B; i += 256) slots[i] = 0ULL;
    }
}

// ---------------------------------------------------------------------------
// 16a x 256t tile, LDS-lean inner loop:
//  - du read via wave-uniform scalar loads (SMEM pipe)
//  - res via register sliding window fed by 1 aligned ds_read_b128 per k-quad
// History (steps 1..nh) replayed onto the staged window with explicit
// mul-then-sub (np order). Per-acc FMA order = k ascending -> bit-identical.
__device__ inline unsigned long long tile_fast(
    const float* __restrict__ res, const float* __restrict__ du,
    int seq, int a_base, int t0, int tid,
    float* res_sh, float* rv_sh, int* ri_sh,
    const float* val_h, const int* ti_h, const int* ai_h, int nh) {

    const float* resS = res + seq * T_DIM;
    for (int i = tid; i < RS_PAD; i += 256) {
        int t = t0 + i - K_DIM / 2;
        float v = 0.0f;
        if (t >= 0 && t < T_DIM && i < TT + K_DIM - 1) {
            v = resS[t];
            for (int s = 0; s < nh; s++) {
                int dk = t - (ti_h[s] - K_DIM / 2);
                if (dk >= 0 && dk < K_DIM)
                    v = __fsub_rn(v, __fmul_rn(val_h[s], du[ai_h[s] * K_DIM + dk]));
            }
        }
        res_sh[i] = v;
    }
    __syncthreads();

    int tg = tid & 63;                                     // 4 consecutive t per lane
    int ag = __builtin_amdgcn_readfirstlane(tid >> 6);     // uniform -> s_load du
    const float* duP = du + (a_base + ag * 4) * K_DIM;

    float acc[4][4];
    #pragma unroll
    for (int i = 0; i < 4; i++)
        #pragma unroll
        for (int j = 0; j < 4; j++) acc[i][j] = 0.0f;

    float r[8];
    *(float4*)&r[0] = *(const float4*)&res_sh[4 * tg];
    *(float4*)&r[4] = *(const float4*)&res_sh[4 * tg + 4];

    #pragma unroll 4
    for (int k = 0; k < K_DIM; k += 4) {
        float dA[4][4];
        #pragma unroll
        for (int i = 0; i < 4; i++)
            *(float4*)dA[i] = *(const float4*)(duP + i * K_DIM + k);  // uniform -> SGPR
        #pragma unroll
        for (int dk = 0; dk < 4; dk++) {
            #pragma unroll
            for (int i = 0; i < 4; i++) {
                float s = dA[i][dk];
                #pragma unroll
                for (int j = 0; j < 4; j++)
                    acc[i][j] = fmaf(s, r[j + dk], acc[i][j]);
            }
        }
        r[0] = r[4]; r[1] = r[5]; r[2] = r[6]; r[3] = r[7];
        *(float4*)&r[4] = *(const float4*)&res_sh[4 * tg + k + 8];  // aligned b128
    }

    // per-thread argmax, ascending flat index (i outer, j inner)
    float bv = -INFINITY;
    int bi = 0x7fffffff;
    #pragma unroll
    for (int i = 0; i < 4; i++) {
        int a = a_base + ag * 4 + i;
        #pragma unroll
        for (int j = 0; j < 4; j++) {
            int t = t0 + 4 * tg + j;
            int fi = a * T_DIM + t;
            float v = acc[i][j];
            if (v > bv || (v == bv && fi < bi)) { bv = v; bi = fi; }
        }
    }
    rv_sh[tid] = bv;
    ri_sh[tid] = bi;
    __syncthreads();
    for (int off = 128; off > 0; off >>= 1) {
        if (tid < off) {
            float v2 = rv_sh[tid + off]; int i2 = ri_sh[tid + off];
            if (v2 > rv_sh[tid] || (v2 == rv_sh[tid] && i2 < ri_sh[tid])) {
                rv_sh[tid] = v2; ri_sh[tid] = i2;
            }
        }
        __syncthreads();
    }
    return pack_vi(rv_sh[0], ri_sh[0]);
}

// ---------------------------------------------------------------------------
// step 0: 512 blocks/seq; last arrival reduces pmax, finalizes step 0 into
// global res/emb and publishes the step-1 dirty window.
__global__ __launch_bounds__(256) void k_step_full(
    float* __restrict__ res, const float* __restrict__ du,
    const float* __restrict__ ae, float* __restrict__ emb,
    unsigned long long* __restrict__ pmax, int* __restrict__ cnt,
    int* __restrict__ dirty0) {

    int seq = blockIdx.y;
    int blk = blockIdx.x;                 // 0..511 = atile*64 + ttile
    int a_base = (blk >> 6) * ATI;
    int t0 = (blk & 63) * TT;
    int tid = threadIdx.x;

    alignas(16) __shared__ float res_sh[RS_PAD];
    __shared__ float rv_sh[256];
    __shared__ int   ri_sh[256];
    __shared__ unsigned long long pm_sh[256];
    __shared__ int last_flag;

    unsigned long long p = tile_fast(res, du, seq, a_base, t0, tid,
                                     res_sh, rv_sh, ri_sh,
                                     nullptr, nullptr, nullptr, 0);
    if (tid == 0) {
        pmax[seq * NPT + blk] = p;
        __threadfence();
        last_flag = (atomicAdd(&cnt[seq], 1) == NPT - 1);
    }
    __syncthreads();
    if (!last_flag) return;

    __threadfence();
    {
        unsigned long long m0 = pmax[seq * NPT + tid];
        unsigned long long m1 = pmax[seq * NPT + 256 + tid];
        pm_sh[tid] = m0 > m1 ? m0 : m1;
    }
    __syncthreads();
    for (int off = 128; off > 0; off >>= 1) {
        if (tid < off) { if (pm_sh[tid + off] > pm_sh[tid]) pm_sh[tid] = pm_sh[tid + off]; }
        __syncthreads();
    }
    float value; int fi;
    unpack_vi(pm_sh[0], &value, &fi);
    int ai = fi >> 14;
    int ti = fi & (T_DIM - 1);
    int pos_idx = value > 0.0f ? ti : 0;
    int atom_idx = value > 0.0f ? ai : 0;

    float* e = emb + (seq * N_STEPS + 0) * 128;
    if (tid == 0) {
        e[0] = ((float)pos_idx / (float)(T_DIM - 1)) * 20.0f;
        e[1] = value;
        int nlo = ti - (K_DIM - 1); if (nlo < 0) nlo = 0;
        int nhi = ti + K_DIM;       if (nhi > T_DIM) nhi = T_DIM;
        dirty0[seq * 2 + 0] = nlo;
        dirty0[seq * 2 + 1] = nhi;
    }
    if (tid >= 2 && tid < 2 + E_DIM) e[tid] = ae[atom_idx * E_DIM + tid - 2];
    if (tid >= 128) {
        int k = tid - 128;
        int t = ti + k - K_DIM / 2;
        if (t >= 0 && t < T_DIM) {
            float r = res[seq * T_DIM + t];
            res[seq * T_DIM + t] = __fsub_rn(r, __fmul_rn(value, du[ai * K_DIM + k]));
        }
    }
}

// ---------------------------------------------------------------------------
// persistent steps 1..15. Cross-block traffic = one u64 mailbox per block per
// step (atomicExch publish, atomicAdd(p,0) coherent polls). NO fences.
__global__ __launch_bounds__(256) void k_inc(
    float* __restrict__ res, const float* __restrict__ du,
    const float* __restrict__ ae, float* __restrict__ emb,
    const unsigned long long* __restrict__ pmax,
    unsigned long long* __restrict__ slots, const int* __restrict__ dirty0) {

    int seq = blockIdx.y;
    int blk = blockIdx.x;                 // 0..15
    int atile = blk >> 1;
    int par = blk & 1;
    int a_base = atile * ATI;
    int tid = threadIdx.x;

    alignas(16) __shared__ float res_sh[RS_PAD];
    __shared__ float rv_sh[256];
    __shared__ int   ri_sh[256];
    __shared__ unsigned long long tmax[32];    // owned ttiles: par, par+2, ...
    __shared__ unsigned long long poll_sh[INC_B];
    __shared__ float val_h[N_STEPS - 1];
    __shared__ int   ti_h[N_STEPS - 1];
    __shared__ int   ai_h[N_STEPS - 1];
    __shared__ int   lo_sh, hi_sh;

    if (tid < 32) tmax[tid] = pmax[seq * NPT + atile * NTT + par + 2 * tid];
    int lo = dirty0[seq * 2 + 0];
    int hi = dirty0[seq * 2 + 1];
    __syncthreads();

    for (int step = 1; step < N_STEPS; step++) {
        int T0 = lo >> 8;
        int tt = ((T0 & 1) == par) ? T0 : T0 + 1;   // my-parity candidate
        bool valid = (tt < NTT) && (tt * TT < hi);  // overlaps dirty window?

        if (valid) {
            unsigned long long p = tile_fast(res, du, seq, a_base, tt * TT,
                                             tid, res_sh, rv_sh, ri_sh,
                                             val_h, ti_h, ai_h, step - 1);
            if (tid == 0) tmax[(tt - par) >> 1] = p;
        }
        if (tid == 0) {
            unsigned long long m = tmax[0];
            for (int j = 1; j < 32; j++) if (tmax[j] > m) m = tmax[j];
            atomicExch(&slots[((step - 1) * NSEQ + seq) * INC_B + blk], m);
        }
        if (tid < INC_B) {
            unsigned long long* sp = &slots[((step - 1) * NSEQ + seq) * INC_B + tid];
            unsigned long long v = atomicAdd(sp, 0ULL);
            while (v == 0ULL) { __builtin_amdgcn_s_sleep(2); v = atomicAdd(sp, 0ULL); }
            poll_sh[tid] = v;
        }
        __syncthreads();
        if (tid == 0) {
            unsigned long long w = poll_sh[0];
            for (int j = 1; j < INC_B; j++) if (poll_sh[j] > w) w = poll_sh[j];
            float value; int fi;
            unpack_vi(w, &value, &fi);
            int ti = fi & (T_DIM - 1);
            val_h[step - 1] = value;
            ti_h[step - 1] = ti;
            ai_h[step - 1] = fi >> 14;
            int nlo = ti - (K_DIM - 1); if (nlo < 0) nlo = 0;
            int nhi = ti + K_DIM;       if (nhi > T_DIM) nhi = T_DIM;
            lo_sh = nlo; hi_sh = nhi;
        }
        __syncthreads();

        if (blk == 0) {   // emb row for this step
            float value = val_h[step - 1];
            int ti = ti_h[step - 1], ai = ai_h[step - 1];
            int pos_idx = value > 0.0f ? ti : 0;
            int atom_idx = value > 0.0f ? ai : 0;
            float* e = emb + (seq * N_STEPS + step) * 128;
            if (tid == 0) {
                e[0] = ((float)pos_idx / (float)(T_DIM - 1)) * 20.0f;
                e[1] = value;
            }
            if (tid >= 2 && tid < 128) e[tid] = ae[atom_idx * E_DIM + tid - 2];
        }
        lo = lo_sh; hi = hi_sh;
    }

    // write final res (updates 1..15, in step order) so k_tail sees it
    if (blk == 0) {
        __syncthreads();
        for (int s = 0; s < N_STEPS - 1; s++) {
            if (tid < 128) {
                int t = ti_h[s] - K_DIM / 2 + tid;
                if (t >= 0 && t < T_DIM) {
                    float r = res[seq * T_DIM + t];
                    res[seq * T_DIM + t] =
                        __fsub_rn(r, __fmul_rn(val_h[s], du[ai_h[s] * K_DIM + tid]));
                }
            }
            __syncthreads();
        }
    }
}

// ---------------------------------------------------------------------------
// norms + ordering + loss; 1 block x 1024 threads
__global__ __launch_bounds__(1024) void k_tail(
    const float* __restrict__ res, const float* __restrict__ emb,
    const float* __restrict__ proj, float* __restrict__ out) {
    int tid = threadIdx.x;
    __shared__ float sh[1024];
    __shared__ float norms[NSEQ];
    __shared__ float keys[NSEQ][N_STEPS];
    __shared__ int   order[NSEQ][N_STEPS];

    {
        int seq = tid >> 8;
        int ln  = tid & 255;
        const float4* r4 = (const float4*)(res + seq * T_DIM);
        float s = 0.0f;
        #pragma unroll
        for (int j = 0; j < 16; j++) {
            float4 v = r4[j * 256 + ln];
            s = fmaf(v.x, v.x, s); s = fmaf(v.y, v.y, s);
            s = fmaf(v.z, v.z, s); s = fmaf(v.w, v.w, s);
        }
        sh[tid] = s;
        __syncthreads();
        for (int off = 128; off > 0; off >>= 1) {
            if (ln < off) sh[tid] += sh[tid + off];
            __syncthreads();
        }
        if (ln == 0) norms[seq] = sqrtf(sh[tid]);
        __syncthreads();
    }
    {
        int pair = tid >> 4;
        int seq = pair >> 4, st = pair & 15;
        int ln = tid & 15;
        const float* e = emb + (seq * N_STEPS + st) * 128 + ln * 8;
        const float* pr = proj + ln * 8;
        float kk = 0.0f;
        #pragma unroll
        for (int dd = 0; dd < 8; dd++) kk = fmaf(e[dd], pr[dd], kk);
        sh[tid] = kk;
        __syncthreads();
        for (int off = 8; off > 0; off >>= 1) {
            if (ln < off) sh[tid] += sh[tid + off];
            __syncthreads();
        }
        if (ln == 0) keys[seq][st] = sh[tid];
        __syncthreads();
    }
    if (tid < NSEQ) {
        int ord[N_STEPS];
        for (int i = 0; i < N_STEPS; i++) ord[i] = i;
        for (int i = 1; i < N_STEPS; i++) {
            int oi = ord[i];
            float kv = keys[tid][oi];
            int j = i - 1;
            while (j >= 0 && keys[tid][ord[j]] > kv) { ord[j + 1] = ord[j]; j--; }
            ord[j + 1] = oi;
        }
        for (int i = 0; i < N_STEPS; i++) order[tid][i] = ord[i];
    }
    __syncthreads();
    float s = 0.0f;
    #pragma unroll
    for (int t = 0; t < 4; t++) {
        int idx = tid + t * 1024;
        int b  = idx >> 11;
        int st = (idx >> 7) & 15;
        int dd = idx & 127;
        float va = emb[((b    ) * N_STEPS + order[b    ][st]) * 128 + dd];
        float vb = emb[((2 + b) * N_STEPS + order[2 + b][st]) * 128 + dd];
        float df = va - vb;
        s = fmaf(df, df, s);
    }
    sh[tid] = s;
    __syncthreads();
    for (int off = 512; off > 0; off >>= 1) {
        if (tid < off) sh[tid] += sh[tid + off];
        __syncthreads();
    }
    if (tid == 0) {
        float mse = sh[0] / 4096.0f;
        float mad = 0.5f * (fabsf(norms[0] - norms[2]) + fabsf(norms[1] - norms[3]));
        out[0] = mse + mad;
    }
}

// ---------------------------------------------------------------------------
extern "C" void kernel_launch(void* const* d_in, const int* in_sizes, int n_in,
                              void* d_out, int out_size, void* d_ws, size_t ws_size,
                              hipStream_t stream) {
    const float* a    = (const float*)d_in[0];
    const float* b    = (const float*)d_in[1];
    const float* d    = (const float*)d_in[2];
    const float* ae   = (const float*)d_in[3];
    const float* proj = (const float*)d_in[4];
    float* out = (float*)d_out;

    float* ws  = (float*)d_ws;
    float* res = ws;                              // 65536 f
    float* du  = res + NSEQ * T_DIM;              // 16384 f
    float* emb = du + A_DIM * K_DIM;              // 8192 f
    unsigned long long* pmax  = (unsigned long long*)(emb + NSEQ * N_STEPS * 128); // 2048 u64
    unsigned long long* slots = pmax + NSEQ * NPT;                                 // 960 u64
    int* cnt    = (int*)(slots + (N_STEPS - 1) * NSEQ * INC_B);
    int* dirty0 = cnt + NSEQ;                     // 8 ints

    k_prep<<<385, 256, 0, stream>>>(d, a, b, du, res, cnt, slots);

    dim3 gfull(NPT, NSEQ);
    k_step_full<<<gfull, 256, 0, stream>>>(res, du, ae, emb, pmax, cnt, dirty0);

    dim3 ginc(INC_B, NSEQ);
    k_inc<<<ginc, 256, 0, stream>>>(res, du, ae, emb, pmax, slots, dirty0);

    k_tail<<<1, 1024, 0, stream>>>(res, emb, proj, out);
}

// Round 7
// 252.076 us; speedup vs baseline: 1.7875x; 1.0333x over previous
//
#include <hip/hip_runtime.h>
#include <math.h>

#define T_DIM 16384
#define A_DIM 128
#define K_DIM 128
#define N_STEPS 16
#define E_DIM 126
#define NSEQ 4

// tiles: 16 atoms x 256 t -> 8 atiles x 64 ttiles = 512 tiles/seq
#define ATI 16
#define TT 256
#define NTT 64
#define NPT 512
#define INC_B 16     // inc blocks per seq: (atile 0..7) x (ttile parity 0..1)
#define RS_PAD 392   // staged res window: 383 used, padded

// order-preserving pack: bigger u64 == (bigger value, then smaller flat idx).
// Never 0 for finite fm values -> 0 is the "empty mailbox" sentinel.
__device__ inline unsigned long long pack_vi(float v, int fi) {
    unsigned int b = __float_as_uint(v);
    b = (b & 0x80000000u) ? ~b : (b | 0x80000000u);
    return ((unsigned long long)b << 32) | (unsigned int)(~fi);
}
__device__ inline void unpack_vi(unsigned long long p, float* v, int* fi) {
    unsigned int lo = (unsigned int)(p & 0xffffffffu);
    unsigned int b = (unsigned int)(p >> 32);
    unsigned int fb = (b & 0x80000000u) ? (b & 0x7fffffffu) : ~b;
    *v = __uint_as_float(fb);
    *fi = (int)(~lo);
}

// ---------------------------------------------------------------------------
// blocks 0..127: d_unit rows; 128..383: res init; 384: zero cnt + mailboxes
__global__ __launch_bounds__(256) void k_prep(
    const float* __restrict__ d, const float* __restrict__ a,
    const float* __restrict__ b, float* __restrict__ du,
    float* __restrict__ res, int* __restrict__ cnt,
    unsigned long long* __restrict__ slots) {
    int blk = blockIdx.x, tid = threadIdx.x;
    if (blk < 128) {
        __shared__ float s[128];
        float v = 0.0f;
        if (tid < 128) { v = d[blk * K_DIM + tid]; s[tid] = v * v; }
        __syncthreads();
        for (int off = 64; off > 0; off >>= 1) {
            if (tid < off) s[tid] += s[tid + off];
            __syncthreads();
        }
        if (tid < 128) du[blk * K_DIM + tid] = v / (sqrtf(s[0]) + 1e-8f);
    } else if (blk < 384) {
        int i = (blk - 128) * 256 + tid;      // 0..65535
        res[i] = (i < 2 * T_DIM) ? a[i] : b[i - 2 * T_DIM];
    } else {
        if (tid < NSEQ) cnt[tid] = 0;
        for (int i = tid; i < (N_STEPS - 1) * NSEQ * INC_B; i += 256) slots[i] = 0ULL;
    }
}

// ---------------------------------------------------------------------------
// 16a x 256t tile:
//  - du via wave-uniform scalar loads (SMEM pipe, zero LDS/VMEM in loop)
//  - res via register sliding window fed by 2x ds_read_b64 per k-quad
//    (8B/lane stride: 16 consecutive lanes cover 32 banks once -> conflict-free)
//  - argmax: per-wave shfl butterfly, 4-entry LDS combine (2 barriers).
// History (steps 1..nh) replayed onto the staged window with explicit
// mul-then-sub (np order). Per-acc FMA order = k ascending -> bit-identical.
__device__ inline unsigned long long tile_fast(
    const float* __restrict__ res, const float* __restrict__ du,
    int seq, int a_base, int t0, int tid,
    float* res_sh, unsigned long long* red4,
    const float* val_h, const int* ti_h, const int* ai_h, int nh) {

    const float* resS = res + seq * T_DIM;
    for (int i = tid; i < RS_PAD; i += 256) {
        int t = t0 + i - K_DIM / 2;
        float v = 0.0f;
        if (t >= 0 && t < T_DIM && i < TT + K_DIM - 1) {
            v = resS[t];
            for (int s = 0; s < nh; s++) {
                int dk = t - (ti_h[s] - K_DIM / 2);
                if (dk >= 0 && dk < K_DIM)
                    v = __fsub_rn(v, __fmul_rn(val_h[s], du[ai_h[s] * K_DIM + dk]));
            }
        }
        res_sh[i] = v;
    }
    __syncthreads();

    int tg = tid & 63;                                     // 4 consecutive t per lane
    int ag = __builtin_amdgcn_readfirstlane(tid >> 6);     // uniform -> s_load du
    const float* duP = du + (a_base + ag * 4) * K_DIM;

    float acc[4][4];
    #pragma unroll
    for (int i = 0; i < 4; i++)
        #pragma unroll
        for (int j = 0; j < 4; j++) acc[i][j] = 0.0f;

    float r[8];
    *(float2*)&r[0] = *(const float2*)&res_sh[4 * tg + 0];
    *(float2*)&r[2] = *(const float2*)&res_sh[4 * tg + 2];
    *(float2*)&r[4] = *(const float2*)&res_sh[4 * tg + 4];
    *(float2*)&r[6] = *(const float2*)&res_sh[4 * tg + 6];

    #pragma unroll 4
    for (int k = 0; k < K_DIM; k += 4) {
        float dA[4][4];
        #pragma unroll
        for (int i = 0; i < 4; i++)
            *(float4*)dA[i] = *(const float4*)(duP + i * K_DIM + k);  // uniform -> SGPR
        #pragma unroll
        for (int dk = 0; dk < 4; dk++) {
            #pragma unroll
            for (int i = 0; i < 4; i++) {
                float s = dA[i][dk];
                #pragma unroll
                for (int j = 0; j < 4; j++)
                    acc[i][j] = fmaf(s, r[j + dk], acc[i][j]);
            }
        }
        r[0] = r[4]; r[1] = r[5]; r[2] = r[6]; r[3] = r[7];
        *(float2*)&r[4] = *(const float2*)&res_sh[4 * tg + k + 8];   // b64, no conflicts
        *(float2*)&r[6] = *(const float2*)&res_sh[4 * tg + k + 10];
    }

    // per-thread argmax, ascending flat index (i outer, j inner)
    float bv = -INFINITY;
    int bi = 0x7fffffff;
    #pragma unroll
    for (int i = 0; i < 4; i++) {
        int a = a_base + ag * 4 + i;
        #pragma unroll
        for (int j = 0; j < 4; j++) {
            int t = t0 + 4 * tg + j;
            int fi = a * T_DIM + t;
            float v = acc[i][j];
            if (v > bv || (v == bv && fi < bi)) { bv = v; bi = fi; }
        }
    }
    // wave butterfly (no barriers)
    #pragma unroll
    for (int off = 32; off > 0; off >>= 1) {
        float v2 = __shfl_down(bv, off);
        int   i2 = __shfl_down(bi, off);
        if (v2 > bv || (v2 == bv && i2 < bi)) { bv = v2; bi = i2; }
    }
    if ((tid & 63) == 0) red4[tid >> 6] = pack_vi(bv, bi);
    __syncthreads();
    if (tid == 0) {
        unsigned long long m = red4[0];
        #pragma unroll
        for (int w = 1; w < 4; w++) if (red4[w] > m) m = red4[w];
        red4[0] = m;
    }
    __syncthreads();
    return red4[0];
}

// ---------------------------------------------------------------------------
// step 0: 512 blocks/seq; last arrival reduces pmax, finalizes step 0 into
// global res/emb and publishes the step-1 dirty window.
__global__ __launch_bounds__(256) void k_step_full(
    float* __restrict__ res, const float* __restrict__ du,
    const float* __restrict__ ae, float* __restrict__ emb,
    unsigned long long* __restrict__ pmax, int* __restrict__ cnt,
    int* __restrict__ dirty0) {

    int seq = blockIdx.y;
    int blk = blockIdx.x;                 // 0..511 = atile*64 + ttile
    int a_base = (blk >> 6) * ATI;
    int t0 = (blk & 63) * TT;
    int tid = threadIdx.x;

    alignas(16) __shared__ float res_sh[RS_PAD];
    __shared__ unsigned long long red4[4];
    __shared__ unsigned long long pm_sh[256];
    __shared__ int last_flag;

    unsigned long long p = tile_fast(res, du, seq, a_base, t0, tid,
                                     res_sh, red4, nullptr, nullptr, nullptr, 0);
    if (tid == 0) {
        pmax[seq * NPT + blk] = p;
        __threadfence();
        last_flag = (atomicAdd(&cnt[seq], 1) == NPT - 1);
    }
    __syncthreads();
    if (!last_flag) return;

    __threadfence();
    {
        unsigned long long m0 = pmax[seq * NPT + tid];
        unsigned long long m1 = pmax[seq * NPT + 256 + tid];
        pm_sh[tid] = m0 > m1 ? m0 : m1;
    }
    __syncthreads();
    for (int off = 128; off > 0; off >>= 1) {
        if (tid < off) { if (pm_sh[tid + off] > pm_sh[tid]) pm_sh[tid] = pm_sh[tid + off]; }
        __syncthreads();
    }
    float value; int fi;
    unpack_vi(pm_sh[0], &value, &fi);
    int ai = fi >> 14;
    int ti = fi & (T_DIM - 1);
    int pos_idx = value > 0.0f ? ti : 0;
    int atom_idx = value > 0.0f ? ai : 0;

    float* e = emb + (seq * N_STEPS + 0) * 128;
    if (tid == 0) {
        e[0] = ((float)pos_idx / (float)(T_DIM - 1)) * 20.0f;
        e[1] = value;
        int nlo = ti - (K_DIM - 1); if (nlo < 0) nlo = 0;
        int nhi = ti + K_DIM;       if (nhi > T_DIM) nhi = T_DIM;
        dirty0[seq * 2 + 0] = nlo;
        dirty0[seq * 2 + 1] = nhi;
    }
    if (tid >= 2 && tid < 2 + E_DIM) e[tid] = ae[atom_idx * E_DIM + tid - 2];
    if (tid >= 128) {
        int k = tid - 128;
        int t = ti + k - K_DIM / 2;
        if (t >= 0 && t < T_DIM) {
            float r = res[seq * T_DIM + t];
            res[seq * T_DIM + t] = __fsub_rn(r, __fmul_rn(value, du[ai * K_DIM + k]));
        }
    }
}

// ---------------------------------------------------------------------------
// persistent steps 1..15. Cross-block traffic = one u64 mailbox per block per
// step. Publish: atomicExch (coherent). Poll: RELAXED agent-scope atomic
// loads (coherent reads, no RMW serialization, no fences). The mailbox value
// is the entire message, so no other memory ordering is required.
__global__ __launch_bounds__(256) void k_inc(
    float* __restrict__ res, const float* __restrict__ du,
    const float* __restrict__ ae, float* __restrict__ emb,
    const unsigned long long* __restrict__ pmax,
    unsigned long long* __restrict__ slots, const int* __restrict__ dirty0) {

    int seq = blockIdx.y;
    int blk = blockIdx.x;                 // 0..15
    int atile = blk >> 1;
    int par = blk & 1;
    int a_base = atile * ATI;
    int tid = threadIdx.x;

    alignas(16) __shared__ float res_sh[RS_PAD];
    __shared__ unsigned long long red4[4];
    __shared__ unsigned long long tmax[32];    // owned ttiles: par, par+2, ...
    __shared__ unsigned long long poll_sh[INC_B];
    __shared__ float val_h[N_STEPS - 1];
    __shared__ int   ti_h[N_STEPS - 1];
    __shared__ int   ai_h[N_STEPS - 1];
    __shared__ int   lo_sh, hi_sh;

    if (tid < 32) tmax[tid] = pmax[seq * NPT + atile * NTT + par + 2 * tid];
    int lo = dirty0[seq * 2 + 0];
    int hi = dirty0[seq * 2 + 1];
    __syncthreads();

    for (int step = 1; step < N_STEPS; step++) {
        int T0 = lo >> 8;
        int tt = ((T0 & 1) == par) ? T0 : T0 + 1;   // my-parity candidate
        bool valid = (tt < NTT) && (tt * TT < hi);  // overlaps dirty window?

        if (valid) {
            unsigned long long p = tile_fast(res, du, seq, a_base, tt * TT,
                                             tid, res_sh, red4,
                                             val_h, ti_h, ai_h, step - 1);
            if (tid == 0) tmax[(tt - par) >> 1] = p;
        }
        if (tid == 0) {
            unsigned long long m = tmax[0];
            for (int j = 1; j < 32; j++) if (tmax[j] > m) m = tmax[j];
            atomicExch(&slots[((step - 1) * NSEQ + seq) * INC_B + blk], m);
        }
        if (tid < INC_B) {
            const unsigned long long* sp =
                &slots[((step - 1) * NSEQ + seq) * INC_B + tid];
            unsigned long long v = __hip_atomic_load(sp, __ATOMIC_RELAXED,
                                                     __HIP_MEMORY_SCOPE_AGENT);
            while (v == 0ULL) {
                __builtin_amdgcn_s_sleep(1);
                v = __hip_atomic_load(sp, __ATOMIC_RELAXED,
                                      __HIP_MEMORY_SCOPE_AGENT);
            }
            poll_sh[tid] = v;
        }
        __syncthreads();
        if (tid == 0) {
            unsigned long long w = poll_sh[0];
            for (int j = 1; j < INC_B; j++) if (poll_sh[j] > w) w = poll_sh[j];
            float value; int fi;
            unpack_vi(w, &value, &fi);
            int ti = fi & (T_DIM - 1);
            val_h[step - 1] = value;
            ti_h[step - 1] = ti;
            ai_h[step - 1] = fi >> 14;
            int nlo = ti - (K_DIM - 1); if (nlo < 0) nlo = 0;
            int nhi = ti + K_DIM;       if (nhi > T_DIM) nhi = T_DIM;
            lo_sh = nlo; hi_sh = nhi;
        }
        __syncthreads();

        if (blk == 0) {   // emb row for this step
            float value = val_h[step - 1];
            int ti = ti_h[step - 1], ai = ai_h[step - 1];
            int pos_idx = value > 0.0f ? ti : 0;
            int atom_idx = value > 0.0f ? ai : 0;
            float* e = emb + (seq * N_STEPS + step) * 128;
            if (tid == 0) {
                e[0] = ((float)pos_idx / (float)(T_DIM - 1)) * 20.0f;
                e[1] = value;
            }
            if (tid >= 2 && tid < 128) e[tid] = ae[atom_idx * E_DIM + tid - 2];
        }
        lo = lo_sh; hi = hi_sh;
    }

    // write final res (updates 1..15, in step order) so k_tail sees it
    if (blk == 0) {
        __syncthreads();
        for (int s = 0; s < N_STEPS - 1; s++) {
            if (tid < 128) {
                int t = ti_h[s] - K_DIM / 2 + tid;
                if (t >= 0 && t < T_DIM) {
                    float r = res[seq * T_DIM + t];
                    res[seq * T_DIM + t] =
                        __fsub_rn(r, __fmul_rn(val_h[s], du[ai_h[s] * K_DIM + tid]));
                }
            }
            __syncthreads();
        }
    }
}

// ---------------------------------------------------------------------------
// norms + ordering + loss; 1 block x 1024 threads
__global__ __launch_bounds__(1024) void k_tail(
    const float* __restrict__ res, const float* __restrict__ emb,
    const float* __restrict__ proj, float* __restrict__ out) {
    int tid = threadIdx.x;
    __shared__ float sh[1024];
    __shared__ float norms[NSEQ];
    __shared__ float keys[NSEQ][N_STEPS];
    __shared__ int   order[NSEQ][N_STEPS];

    {
        int seq = tid >> 8;
        int ln  = tid & 255;
        const float4* r4 = (const float4*)(res + seq * T_DIM);
        float s = 0.0f;
        #pragma unroll
        for (int j = 0; j < 16; j++) {
            float4 v = r4[j * 256 + ln];
            s = fmaf(v.x, v.x, s); s = fmaf(v.y, v.y, s);
            s = fmaf(v.z, v.z, s); s = fmaf(v.w, v.w, s);
        }
        sh[tid] = s;
        __syncthreads();
        for (int off = 128; off > 0; off >>= 1) {
            if (ln < off) sh[tid] += sh[tid + off];
            __syncthreads();
        }
        if (ln == 0) norms[seq] = sqrtf(sh[tid]);
        __syncthreads();
    }
    {
        int pair = tid >> 4;
        int seq = pair >> 4, st = pair & 15;
        int ln = tid & 15;
        const float* e = emb + (seq * N_STEPS + st) * 128 + ln * 8;
        const float* pr = proj + ln * 8;
        float kk = 0.0f;
        #pragma unroll
        for (int dd = 0; dd < 8; dd++) kk = fmaf(e[dd], pr[dd], kk);
        sh[tid] = kk;
        __syncthreads();
        for (int off = 8; off > 0; off >>= 1) {
            if (ln < off) sh[tid] += sh[tid + off];
            __syncthreads();
        }
        if (ln == 0) keys[seq][st] = sh[tid];
        __syncthreads();
    }
    if (tid < NSEQ) {
        int ord[N_STEPS];
        for (int i = 0; i < N_STEPS; i++) ord[i] = i;
        for (int i = 1; i < N_STEPS; i++) {
            int oi = ord[i];
            float kv = keys[tid][oi];
            int j = i - 1;
            while (j >= 0 && keys[tid][ord[j]] > kv) { ord[j + 1] = ord[j]; j--; }
            ord[j + 1] = oi;
        }
        for (int i = 0; i < N_STEPS; i++) order[tid][i] = ord[i];
    }
    __syncthreads();
    float s = 0.0f;
    #pragma unroll
    for (int t = 0; t < 4; t++) {
        int idx = tid + t * 1024;
        int b  = idx >> 11;
        int st = (idx >> 7) & 15;
        int dd = idx & 127;
        float va = emb[((b    ) * N_STEPS + order[b    ][st]) * 128 + dd];
        float vb = emb[((2 + b) * N_STEPS + order[2 + b][st]) * 128 + dd];
        float df = va - vb;
        s = fmaf(df, df, s);
    }
    sh[tid] = s;
    __syncthreads();
    for (int off = 512; off > 0; off >>= 1) {
        if (tid < off) sh[tid] += sh[tid + off];
        __syncthreads();
    }
    if (tid == 0) {
        float mse = sh[0] / 4096.0f;
        float mad = 0.5f * (fabsf(norms[0] - norms[2]) + fabsf(norms[1] - norms[3]));
        out[0] = mse + mad;
    }
}

// ---------------------------------------------------------------------------
extern "C" void kernel_launch(void* const* d_in, const int* in_sizes, int n_in,
                              void* d_out, int out_size, void* d_ws, size_t ws_size,
                              hipStream_t stream) {
    const float* a    = (const float*)d_in[0];
    const float* b    = (const float*)d_in[1];
    const float* d    = (const float*)d_in[2];
    const float* ae   = (const float*)d_in[3];
    const float* proj = (const float*)d_in[4];
    float* out = (float*)d_out;

    float* ws  = (float*)d_ws;
    float* res = ws;                              // 65536 f
    float* du  = res + NSEQ * T_DIM;              // 16384 f
    float* emb = du + A_DIM * K_DIM;              // 8192 f
    unsigned long long* pmax  = (unsigned long long*)(emb + NSEQ * N_STEPS * 128); // 2048 u64
    unsigned long long* slots = pmax + NSEQ * NPT;                                 // 960 u64
    int* cnt    = (int*)(slots + (N_STEPS - 1) * NSEQ * INC_B);
    int* dirty0 = cnt + NSEQ;                     // 8 ints

    k_prep<<<385, 256, 0, stream>>>(d, a, b, du, res, cnt, slots);

    dim3 gfull(NPT, NSEQ);
    k_step_full<<<gfull, 256, 0, stream>>>(res, du, ae, emb, pmax, cnt, dirty0);

    dim3 ginc(INC_B, NSEQ);
    k_inc<<<ginc, 256, 0, stream>>>(res, du, ae, emb, pmax, slots, dirty0);

    k_tail<<<1, 1024, 0, stream>>>(res, emb, proj, out);
}